// Round 6
// baseline (478.355 us; speedup 1.0000x reference)
//
#include <hip/hip_runtime.h>
#include <hip/hip_bf16.h>
#include <math.h>

#define MEMSZ 32768
#define FDIM  128
#define BATCH 4096

typedef float f32x4 __attribute__((ext_vector_type(4)));
typedef _Float16 f16x8 __attribute__((ext_vector_type(8)));
typedef short bf16x8 __attribute__((ext_vector_type(8)));
typedef unsigned short u16t;
typedef unsigned int u32t;

static __device__ __forceinline__ u16t f2h_bits(float f) {
    union { _Float16 h; u16t u; } c;
    c.h = (_Float16)f;
    return c.u;
}

#define GLDS16(gsrc, ldst) \
  __builtin_amdgcn_global_load_lds((const __attribute__((address_space(1))) void*)(gsrc), \
                                   (__attribute__((address_space(3))) void*)(ldst), 16, 0, 0)

// ---------------- K0: one-pass W read -> partial row sums + bf16 fragment-major W^T ----------------
// Grid: 64 b-tiles x 256 m-tiles. Tile [64 b][128 m] f32 staged swizzled (^((b&7)<<4)).
// Outputs: partial[mt][4096 b] tile row-sums; WT64 chunks = per-lane MFMA A-fragments:
//   chunk ci = wm*256+mf*128+ks*64+(g*16+q16) holds bf16 W[b=ks*32+g*8+e][m=wm*32+mf*16+q16], e=0..7.
__global__ __launch_bounds__(256) void k_sumT(const float* __restrict__ W,
                                              float* __restrict__ partial,
                                              unsigned char* __restrict__ WT64) {
    __shared__ __align__(16) unsigned char xs[32768];
    const int tid = threadIdx.x;
    const int bt = blockIdx.x & 63, mt = blockIdx.x >> 6;

    #pragma unroll
    for (int i = 0; i < 8; ++i) {
        const int gi = tid + i * 256;          // 2048 16B granules: 64 rows x 32
        const int b = gi >> 5;
        const int srcoff = ((gi & 31) * 16) ^ ((b & 7) << 4);   // inverse-swizzled source
        GLDS16((const unsigned char*)W + ((size_t)(bt * 64 + b) * MEMSZ + (size_t)mt * 128) * 4 + srcoff,
               &xs[gi * 16]);
    }
    asm volatile("s_waitcnt vmcnt(0)" ::: "memory");
    __syncthreads();

    // per-b partial sums over this tile's 128 m (swizzle permutes granules within row - sum-safe)
    {
        const int b = tid >> 2, q = tid & 3;
        float s = 0.f;
        #pragma unroll
        for (int j = 0; j < 8; ++j) {
            const int off = b * 512 + ((q * 128 + j * 16) ^ ((b & 7) << 4));
            const float4 v = *reinterpret_cast<const float4*>(&xs[off]);
            s += (v.x + v.y) + (v.z + v.w);
        }
        s += __shfl_xor(s, 1);
        s += __shfl_xor(s, 2);
        if (q == 0) partial[(size_t)mt * BATCH + bt * 64 + b] = s;
    }

    // transpose to bf16 fragment-major chunks
    unsigned char* dst = WT64 + ((size_t)mt * 64 + bt) * 16384;
    #pragma unroll
    for (int k = 0; k < 4; ++k) {
        const int ci = tid + k * 256;          // 1024 chunks
        const int wm = ci >> 8, mf = (ci >> 7) & 1, ks = (ci >> 6) & 1;
        const int l6 = ci & 63, g = l6 >> 4, q16 = l6 & 15;
        const int m = wm * 32 + mf * 16 + q16;
        u32t pk[4];
        #pragma unroll
        for (int h = 0; h < 4; ++h) {
            const int b0 = ks * 32 + g * 8 + 2 * h;
            const float lo = *reinterpret_cast<const float*>(
                &xs[b0 * 512 + ((m * 4) ^ ((b0 & 7) << 4))]);
            const float hi = *reinterpret_cast<const float*>(
                &xs[(b0 + 1) * 512 + ((m * 4) ^ (((b0 + 1) & 7) << 4))]);
            asm("v_cvt_pk_bf16_f32 %0, %1, %2" : "=v"(pk[h]) : "v"(lo), "v"(hi));
        }
        *reinterpret_cast<uint4*>(dst + ci * 16) = make_uint4(pk[0], pk[1], pk[2], pk[3]);
    }
}

// ---------------- K0b: reduce partials -> inv_s ----------------
__global__ __launch_bounds__(256) void k_inv(const float* __restrict__ partial,
                                             float* __restrict__ inv_s) {
    const int b = blockIdx.x * 256 + threadIdx.x;
    float s0 = 0.f, s1 = 0.f, s2 = 0.f, s3 = 0.f;
    for (int mt = 0; mt < 256; mt += 4) {
        s0 += partial[(size_t)mt * BATCH + b];
        s1 += partial[(size_t)(mt + 1) * BATCH + b];
        s2 += partial[(size_t)(mt + 2) * BATCH + b];
        s3 += partial[(size_t)(mt + 3) * BATCH + b];
    }
    inv_s[b] = 1.0f / ((s0 + s1) + (s2 + s3));
}

// ---------------- K1b: XT64 = fragment-major bf16(X * inv_s) ----------------
__global__ __launch_bounds__(256) void k_prep(const float* __restrict__ X,
                                              const float* __restrict__ inv_s,
                                              unsigned char* __restrict__ XT64) {
    __shared__ float xs[64][132];
    const int T = blockIdx.x;
    const int b0 = T * 64;
    const int tid = threadIdx.x;
    #pragma unroll
    for (int i = 0; i < 8; ++i) {
        const int idx = tid + i * 256;
        const int row = idx >> 5, c4 = idx & 31;
        const float s = inv_s[b0 + row];
        float4 v = *reinterpret_cast<const float4*>(&X[(size_t)(b0 + row) * FDIM + c4 * 4]);
        v.x *= s; v.y *= s; v.z *= s; v.w *= s;
        *reinterpret_cast<float4*>(&xs[row][c4 * 4]) = v;
    }
    __syncthreads();
    #pragma unroll
    for (int i = 0; i < 4; ++i) {
        const int L = tid + i * 256;
        const int fh = L >> 9, ff = (L >> 7) & 3, ks = (L >> 6) & 1, ln = L & 63;
        const int f = fh * 64 + ff * 16 + (ln & 15);
        const int bi = ks * 32 + (ln >> 4) * 8;
        u32t pk[4];
        #pragma unroll
        for (int h = 0; h < 4; ++h) {
            const float lo = xs[bi + 2 * h][f];
            const float hi = xs[bi + 2 * h + 1][f];
            asm("v_cvt_pk_bf16_f32 %0, %1, %2" : "=v"(pk[h]) : "v"(lo), "v"(hi));
        }
        *reinterpret_cast<uint4*>(XT64 + (size_t)T * 16384 + (size_t)L * 16) =
            make_uint4(pk[0], pk[1], pk[2], pk[3]);
    }
}

// ---------------- K2 (MFMA, no LDS): MemNew = Mem + W^T @ (X*inv_s), + f16 copies ----------------
// 256 blocks x 512 threads; block tile 128m x 128f; K-step 64 b; 64 K-steps.
// A and B both fragment-major in global -> pure coalesced register loads + MFMA.
// No barriers; explicit 2-deep register double-buffer; compiler emits counted waits.
__global__ __launch_bounds__(512, 2) void k_update_mfma2(
    const unsigned char* __restrict__ WT64, const unsigned char* __restrict__ XT64,
    const float* __restrict__ Mem, float* __restrict__ MemNew,
    u16t* __restrict__ MemH, u16t* __restrict__ MemHT)
{
    const int tid = threadIdx.x;
    const int lane = tid & 63, w = tid >> 6;
    const int q16 = lane & 15, g = lane >> 4;
    const int wm = w >> 1, wf = w & 1;       // wave tile: 32 m x 64 f
    const int mblk = blockIdx.x * 128;

    const unsigned char* wbase = WT64 + (size_t)blockIdx.x * (64 * 16384)
                               + (size_t)(wm * 4096 + lane * 16);
    const unsigned char* xbase = XT64 + (size_t)(wf * 8192 + lane * 16);

    f32x4 acc[2][4];
    #pragma unroll
    for (int mf = 0; mf < 2; ++mf)
        #pragma unroll
        for (int ff = 0; ff < 4; ++ff) acc[mf][ff] = (f32x4){0.f, 0.f, 0.f, 0.f};

    auto issue = [&](bf16x8 (&ar)[2][2], bf16x8 (&br)[4][2], int t) {
        const unsigned char* wp = wbase + (size_t)t * 16384;
        #pragma unroll
        for (int mf = 0; mf < 2; ++mf)
            #pragma unroll
            for (int ks = 0; ks < 2; ++ks)
                ar[mf][ks] = *reinterpret_cast<const bf16x8*>(wp + mf * 2048 + ks * 1024);
        const unsigned char* xp = xbase + (size_t)t * 16384;
        #pragma unroll
        for (int ff = 0; ff < 4; ++ff)
            #pragma unroll
            for (int ks = 0; ks < 2; ++ks)
                br[ff][ks] = *reinterpret_cast<const bf16x8*>(xp + ff * 2048 + ks * 1024);
    };
    auto compute = [&](bf16x8 (&ar)[2][2], bf16x8 (&br)[4][2]) {
        #pragma unroll
        for (int mf = 0; mf < 2; ++mf)
            #pragma unroll
            for (int ff = 0; ff < 4; ++ff)
                #pragma unroll
                for (int ks = 0; ks < 2; ++ks)
                    acc[mf][ff] = __builtin_amdgcn_mfma_f32_16x16x32_bf16(
                        ar[mf][ks], br[ff][ks], acc[mf][ff], 0, 0, 0);
    };

    bf16x8 aE[2][2], bE[4][2], aO[2][2], bO[4][2];
    issue(aE, bE, 0); issue(aO, bO, 1);
    const int NT = BATCH / 64;   // 64, even
    for (int t = 0; t < NT; t += 2) {
        compute(aE, bE);
        if (t + 2 < NT) issue(aE, bE, t + 2);
        compute(aO, bO);
        if (t + 3 < NT) issue(aO, bO, t + 3);
    }

    // epilogue: add memory; write f32 MemNew + f16 MemH + f16-transposed MemHT
    #pragma unroll
    for (int mf = 0; mf < 2; ++mf) {
        #pragma unroll
        for (int ff = 0; ff < 4; ++ff) {
            const int m0 = mblk + wm * 32 + mf * 16 + g * 4;
            const int fcol = wf * 64 + ff * 16 + q16;
            ushort4 ht;
            u16t* htp = reinterpret_cast<u16t*>(&ht);
            #pragma unroll
            for (int r = 0; r < 4; ++r) {
                const size_t idx = (size_t)(m0 + r) * FDIM + fcol;
                const float v = acc[mf][ff][r] + Mem[idx];
                MemNew[idx] = v;
                const u16t hb = f2h_bits(v);
                MemH[idx] = hb;
                htp[r] = hb;
            }
            *reinterpret_cast<ushort4*>(&MemHT[(size_t)fcol * MEMSZ + m0]) = ht;
        }
    }
}

// ---------------- K3 (MFMA f16): flash attention partials over chunks ----------------
__global__ __launch_bounds__(256) void k_attn_mfma(
    const float* __restrict__ Q, const u16t* __restrict__ Kh, const u16t* __restrict__ KhT,
    float* __restrict__ accP, float* __restrict__ mP, float* __restrict__ lP, int s_shift)
{
    __shared__ __align__(16) unsigned char kv_u8[2][16384];
    __shared__ __align__(16) unsigned char v_u8[2][16384];
    __shared__ __align__(16) unsigned char p_u8[4][2048];

    const int tid = threadIdx.x;
    const int w = tid >> 6, lane = tid & 63;
    const int q16 = lane & 15, g = lane >> 4;
    const int S = 1 << s_shift;
    const int s_idx = blockIdx.x & (S - 1);
    const int qb = blockIdx.x >> s_shift;
    const int chunk = MEMSZ >> s_shift;
    const int slot0 = s_idx * chunk;
    const int NT = chunk >> 6;

    f16x8 qfrag[2][4];
    #pragma unroll
    for (int qf = 0; qf < 2; ++qf) {
        const float* qrow = Q + (size_t)(qb * 128 + w * 32 + qf * 16 + q16) * FDIM;
        #pragma unroll
        for (int ks = 0; ks < 4; ++ks) {
            float tmp[8];
            *reinterpret_cast<float4*>(&tmp[0]) = *reinterpret_cast<const float4*>(&qrow[ks * 32 + g * 8]);
            *reinterpret_cast<float4*>(&tmp[4]) = *reinterpret_cast<const float4*>(&qrow[ks * 32 + g * 8 + 4]);
            f16x8 v;
            #pragma unroll
            for (int e = 0; e < 8; ++e) v[e] = (_Float16)tmp[e];
            qfrag[qf][ks] = v;
        }
    }

    auto stage = [&](int buf, int tile) {
        const unsigned char* kbase = (const unsigned char*)Kh + (size_t)(slot0 + tile * 64) * 256;
        const unsigned char* tbase = (const unsigned char*)KhT + (size_t)(slot0 + tile * 64) * 2;
        #pragma unroll
        for (int c = 0; c < 4; ++c) {
            const int C = w * 4 + c;
            const int pp = C * 1024 + lane * 16;
            {
                const int slot = pp >> 8;
                const int inner = (pp & 255) ^ ((slot & 7) << 4);
                GLDS16(kbase + slot * 256 + inner, &kv_u8[buf][C * 1024]);
            }
            {
                const int d = pp >> 7;
                const int inner = (pp & 127) ^ ((d & 7) << 4);
                GLDS16(tbase + (size_t)d * 65536 + inner, &v_u8[buf][C * 1024]);
            }
        }
    };

    float m_run[2] = {-3.0e38f, -3.0e38f};
    float l_run[2] = {0.f, 0.f};
    f32x4 acc_o[8][2];
    #pragma unroll
    for (int df = 0; df < 8; ++df)
        #pragma unroll
        for (int qf = 0; qf < 2; ++qf)
            acc_o[df][qf] = (f32x4){0.f, 0.f, 0.f, 0.f};

    stage(0, 0);
    asm volatile("s_waitcnt vmcnt(0)" ::: "memory");
    __builtin_amdgcn_s_barrier();
    __builtin_amdgcn_sched_barrier(0);

    int cur = 0;
    for (int t = 0; t < NT; ++t) {
        if (t + 1 < NT) stage(cur ^ 1, t + 1);

        f32x4 acc_s[4][2];
        #pragma unroll
        for (int sf = 0; sf < 4; ++sf) {
            acc_s[sf][0] = (f32x4){0.f, 0.f, 0.f, 0.f};
            acc_s[sf][1] = (f32x4){0.f, 0.f, 0.f, 0.f};
        }
        const unsigned char* kvb = &kv_u8[cur][0];
        #pragma unroll
        for (int ks = 0; ks < 4; ++ks) {
            #pragma unroll
            for (int sf = 0; sf < 4; ++sf) {
                const int slot = sf * 16 + q16;
                const f16x8 a = *reinterpret_cast<const f16x8*>(
                    kvb + slot * 256 + ((ks * 64 + g * 16) ^ ((slot & 7) << 4)));
                acc_s[sf][0] = __builtin_amdgcn_mfma_f32_16x16x32_f16(a, qfrag[0][ks], acc_s[sf][0], 0, 0, 0);
                acc_s[sf][1] = __builtin_amdgcn_mfma_f32_16x16x32_f16(a, qfrag[1][ks], acc_s[sf][1], 0, 0, 0);
            }
        }

        f16x8 pb[2][2];
        unsigned char* pw = &p_u8[w][0];
        #pragma unroll
        for (int qf = 0; qf < 2; ++qf) {
            float pmax = acc_s[0][qf][0];
            #pragma unroll
            for (int sf = 0; sf < 4; ++sf)
                #pragma unroll
                for (int r = 0; r < 4; ++r)
                    pmax = fmaxf(pmax, acc_s[sf][qf][r]);
            pmax = fmaxf(pmax, __shfl_xor(pmax, 16));
            pmax = fmaxf(pmax, __shfl_xor(pmax, 32));
            const float mn = fmaxf(m_run[qf], pmax);
            float p[4][4];
            float psum = 0.f;
            #pragma unroll
            for (int sf = 0; sf < 4; ++sf)
                #pragma unroll
                for (int r = 0; r < 4; ++r) {
                    p[sf][r] = __expf(acc_s[sf][qf][r] - mn);
                    psum += p[sf][r];
                }
            psum += __shfl_xor(psum, 16);
            psum += __shfl_xor(psum, 32);
            const float sc = __expf(m_run[qf] - mn);
            l_run[qf] = l_run[qf] * sc + psum;
            m_run[qf] = mn;
            #pragma unroll
            for (int df = 0; df < 8; ++df) {
                acc_o[df][qf][0] *= sc; acc_o[df][qf][1] *= sc;
                acc_o[df][qf][2] *= sc; acc_o[df][qf][3] *= sc;
            }
            #pragma unroll
            for (int sf = 0; sf < 4; ++sf)
                #pragma unroll
                for (int rr = 0; rr < 2; ++rr) {
                    const u32t val = (u32t)f2h_bits(p[sf][2 * rr]) | ((u32t)f2h_bits(p[sf][2 * rr + 1]) << 16);
                    const int byte = q16 * 128 + (((sf * 16 + g * 4 + 2 * rr) * 2) ^ ((q16 & 7) << 4));
                    *reinterpret_cast<u32t*>(pw + byte) = val;
                }
            #pragma unroll
            for (int kk = 0; kk < 2; ++kk) {
                const int byte = q16 * 128 + (((kk * 32 + g * 8) * 2) ^ ((q16 & 7) << 4));
                pb[qf][kk] = *reinterpret_cast<const f16x8*>(pw + byte);
            }
        }

        const unsigned char* vb = &v_u8[cur][0];
        #pragma unroll
        for (int df = 0; df < 8; ++df) {
            #pragma unroll
            for (int kk = 0; kk < 2; ++kk) {
                const int d = df * 16 + q16;
                const f16x8 av = *reinterpret_cast<const f16x8*>(
                    vb + d * 128 + ((kk * 64 + g * 16) ^ ((d & 7) << 4)));
                acc_o[df][0] = __builtin_amdgcn_mfma_f32_16x16x32_f16(av, pb[0][kk], acc_o[df][0], 0, 0, 0);
                acc_o[df][1] = __builtin_amdgcn_mfma_f32_16x16x32_f16(av, pb[1][kk], acc_o[df][1], 0, 0, 0);
            }
        }

        asm volatile("s_waitcnt vmcnt(0)" ::: "memory");
        __builtin_amdgcn_s_barrier();
        __builtin_amdgcn_sched_barrier(0);
        cur ^= 1;
    }

    const int rowbase = qb * 128 + w * 32;
    #pragma unroll
    for (int qf = 0; qf < 2; ++qf) {
        const int row = rowbase + qf * 16 + q16;
        float* ap = accP + ((size_t)s_idx * BATCH + row) * FDIM;
        #pragma unroll
        for (int df = 0; df < 8; ++df) {
            float4 o = {acc_o[df][qf][0], acc_o[df][qf][1], acc_o[df][qf][2], acc_o[df][qf][3]};
            *reinterpret_cast<float4*>(&ap[df * 16 + g * 4]) = o;
        }
        if (g == 0) {
            mP[(size_t)s_idx * BATCH + row] = m_run[qf];
            lP[(size_t)s_idx * BATCH + row] = l_run[qf];
        }
    }
}

// ---------------- K4: combine chunk partials ----------------
__global__ __launch_bounds__(256) void k_combine(const float* __restrict__ mP,
                                                 const float* __restrict__ lP,
                                                 const float* __restrict__ accP,
                                                 float* __restrict__ Out,
                                                 float* __restrict__ Conf, int S) {
    const int row = blockIdx.x * 8 + (threadIdx.x >> 5);
    const int lane = threadIdx.x & 31;
    float mt = -3.0e38f;
    for (int s = 0; s < S; ++s) mt = fmaxf(mt, mP[(size_t)s * BATCH + row]);
    float lt = 0.f;
    for (int s = 0; s < S; ++s) lt += lP[(size_t)s * BATCH + row] * __expf(mP[(size_t)s * BATCH + row] - mt);
    const float inv = 1.0f / lt;
    float4 o = {0.f, 0.f, 0.f, 0.f};
    for (int s = 0; s < S; ++s) {
        const float wgt = __expf(mP[(size_t)s * BATCH + row] - mt);
        const float4 a = *reinterpret_cast<const float4*>(&accP[((size_t)s * BATCH + row) * FDIM + lane * 4]);
        o.x += wgt * a.x; o.y += wgt * a.y; o.z += wgt * a.z; o.w += wgt * a.w;
    }
    float4 res = {o.x * inv, o.y * inv, o.z * inv, o.w * inv};
    *reinterpret_cast<float4*>(&Out[(size_t)row * FDIM + lane * 4]) = res;
    if (lane == 0) Conf[row] = inv;
}

// ---------------- fallback f32 path (round-1, known-good) ----------------
__global__ __launch_bounds__(256) void k_rowsum(const float* __restrict__ W,
                                                float* __restrict__ inv_s) {
    const int row = blockIdx.x;
    const float4* Wr = reinterpret_cast<const float4*>(W + (size_t)row * MEMSZ);
    float acc = 0.f;
    #pragma unroll 4
    for (int i = threadIdx.x; i < MEMSZ / 4; i += 256) {
        float4 v = Wr[i];
        acc += (v.x + v.y) + (v.z + v.w);
    }
    #pragma unroll
    for (int off = 32; off > 0; off >>= 1)
        acc += __shfl_down(acc, off, 64);
    __shared__ float wsum[4];
    const int lane = threadIdx.x & 63, wid = threadIdx.x >> 6;
    if (lane == 0) wsum[wid] = acc;
    __syncthreads();
    if (threadIdx.x == 0)
        inv_s[row] = 1.0f / (wsum[0] + wsum[1] + wsum[2] + wsum[3]);
}

#define K2_IT 16
#define K2_MT 64
__global__ __launch_bounds__(256) void k_update_f32(const float* __restrict__ W,
                                                    const float* __restrict__ X,
                                                    const float* __restrict__ inv_s,
                                                    const float* __restrict__ Mem,
                                                    float* __restrict__ MemNew) {
    __shared__ float w_lds[2][K2_IT][K2_MT];
    __shared__ float x_lds[2][K2_IT][FDIM];
    const int j0 = blockIdx.x * K2_MT;
    const int tid = threadIdx.x;
    const int tf = tid & 15;
    const int tj = tid >> 4;

    float acc[4][8];
    #pragma unroll
    for (int a = 0; a < 4; ++a)
        #pragma unroll
        for (int b = 0; b < 8; ++b) acc[a][b] = 0.f;

    float4 pw, px0, px1;
    float ps0, ps1;
    const int wr = tid >> 4, wc4 = tid & 15;
    const int xr0 = tid >> 5, xc0 = tid & 31;
    const int xr1 = (tid + 256) >> 5, xc1 = tid & 31;

    auto load_tile = [&](int it) {
        const int i0 = it * K2_IT;
        pw  = *reinterpret_cast<const float4*>(&W[(size_t)(i0 + wr) * MEMSZ + j0 + wc4 * 4]);
        px0 = *reinterpret_cast<const float4*>(&X[(size_t)(i0 + xr0) * FDIM + xc0 * 4]);
        ps0 = inv_s[i0 + xr0];
        px1 = *reinterpret_cast<const float4*>(&X[(size_t)(i0 + xr1) * FDIM + xc1 * 4]);
        ps1 = inv_s[i0 + xr1];
    };
    auto write_tile = [&](int buf) {
        *reinterpret_cast<float4*>(&w_lds[buf][wr][wc4 * 4]) = pw;
        float4 v = px0; v.x *= ps0; v.y *= ps0; v.z *= ps0; v.w *= ps0;
        *reinterpret_cast<float4*>(&x_lds[buf][xr0][xc0 * 4]) = v;
        float4 u = px1; u.x *= ps1; u.y *= ps1; u.z *= ps1; u.w *= ps1;
        *reinterpret_cast<float4*>(&x_lds[buf][xr1][xc1 * 4]) = u;
    };

    load_tile(0);
    write_tile(0);
    __syncthreads();
    const int NT = BATCH / K2_IT;
    for (int it = 0; it < NT; ++it) {
        const int cur = it & 1;
        if (it + 1 < NT) load_tile(it + 1);
        #pragma unroll 4
        for (int i = 0; i < K2_IT; ++i) {
            const float4 wv = *reinterpret_cast<const float4*>(&w_lds[cur][i][tj * 4]);
            const float4 xa = *reinterpret_cast<const float4*>(&x_lds[cur][i][tf * 4]);
            const float4 xb = *reinterpret_cast<const float4*>(&x_lds[cur][i][tf * 4 + 64]);
            const float wj[4] = {wv.x, wv.y, wv.z, wv.w};
            #pragma unroll
            for (int a = 0; a < 4; ++a) {
                acc[a][0] += wj[a] * xa.x; acc[a][1] += wj[a] * xa.y;
                acc[a][2] += wj[a] * xa.z; acc[a][3] += wj[a] * xa.w;
                acc[a][4] += wj[a] * xb.x; acc[a][5] += wj[a] * xb.y;
                acc[a][6] += wj[a] * xb.z; acc[a][7] += wj[a] * xb.w;
            }
        }
        if (it + 1 < NT) write_tile(cur ^ 1);
        __syncthreads();
    }
    #pragma unroll
    for (int a = 0; a < 4; ++a) {
        const size_t j = (size_t)j0 + tj * 4 + a;
        const float4 m0 = *reinterpret_cast<const float4*>(&Mem[j * FDIM + tf * 4]);
        const float4 m1 = *reinterpret_cast<const float4*>(&Mem[j * FDIM + tf * 4 + 64]);
        float4 o0 = {acc[a][0] + m0.x, acc[a][1] + m0.y, acc[a][2] + m0.z, acc[a][3] + m0.w};
        float4 o1 = {acc[a][4] + m1.x, acc[a][5] + m1.y, acc[a][6] + m1.z, acc[a][7] + m1.w};
        *reinterpret_cast<float4*>(&MemNew[j * FDIM + tf * 4]) = o0;
        *reinterpret_cast<float4*>(&MemNew[j * FDIM + tf * 4 + 64]) = o1;
    }
}

#define QT 16
#define MT 64
#define LSTR (FDIM + 4)
__global__ __launch_bounds__(256) void k_attn_f32(const float* __restrict__ Q,
                                                  const float* __restrict__ MemNew,
                                                  float* __restrict__ Out,
                                                  float* __restrict__ Conf) {
    __shared__ float mem_lds[MT][LSTR];
    __shared__ float q_lds[QT][LSTR];
    __shared__ float p_lds[QT][MT];
    __shared__ float m_lds[QT], l_lds[QT], scale_lds[QT];

    const int tid = threadIdx.x;
    const int qblk = blockIdx.x * QT;

    #pragma unroll
    for (int r = 0; r < 2; ++r) {
        const int idx = tid + r * 256;
        const int row = idx >> 5, c4 = idx & 31;
        *reinterpret_cast<float4*>(&q_lds[row][c4 * 4]) =
            *reinterpret_cast<const float4*>(&Q[(size_t)(qblk + row) * FDIM + c4 * 4]);
    }
    if (tid < QT) { m_lds[tid] = -3.0e38f; l_lds[tid] = 0.f; }

    const int sq = (tid >> 5) * 2;
    const int sm = tid & 31;
    const int pq = tid >> 4;
    const int pf = (tid & 15) * 4;

    float acc[8];
    #pragma unroll
    for (int e = 0; e < 8; ++e) acc[e] = 0.f;

    for (int mt = 0; mt < MEMSZ / MT; ++mt) {
        __syncthreads();
        const float* src = MemNew + (size_t)mt * MT * FDIM;
        #pragma unroll
        for (int r = 0; r < 8; ++r) {
            const int idx = tid + r * 256;
            const int row = idx >> 5, c4 = idx & 31;
            *reinterpret_cast<float4*>(&mem_lds[row][c4 * 4]) =
                *reinterpret_cast<const float4*>(&src[(size_t)row * FDIM + c4 * 4]);
        }
        const float mold0 = m_lds[sq], mold1 = m_lds[sq + 1];
        __syncthreads();

        float s00 = 0.f, s01 = 0.f, s10 = 0.f, s11 = 0.f;
        #pragma unroll 8
        for (int k = 0; k < FDIM; k += 4) {
            const float4 qa = *reinterpret_cast<const float4*>(&q_lds[sq][k]);
            const float4 qb = *reinterpret_cast<const float4*>(&q_lds[sq + 1][k]);
            const float4 ma = *reinterpret_cast<const float4*>(&mem_lds[sm][k]);
            const float4 mb = *reinterpret_cast<const float4*>(&mem_lds[sm + 32][k]);
            s00 += qa.x*ma.x + qa.y*ma.y + qa.z*ma.z + qa.w*ma.w;
            s01 += qa.x*mb.x + qa.y*mb.y + qa.z*mb.z + qa.w*mb.w;
            s10 += qb.x*ma.x + qb.y*ma.y + qb.z*ma.z + qb.w*ma.w;
            s11 += qb.x*mb.x + qb.y*mb.y + qb.z*mb.z + qb.w*mb.w;
        }
        float r0 = fmaxf(s00, s01), r1 = fmaxf(s10, s11);
        #pragma unroll
        for (int off = 1; off <= 16; off <<= 1) {
            r0 = fmaxf(r0, __shfl_xor(r0, off, 64));
            r1 = fmaxf(r1, __shfl_xor(r1, off, 64));
        }
        const float mn0 = fmaxf(mold0, r0), mn1 = fmaxf(mold1, r1);
        const float p00 = __expf(s00 - mn0), p01 = __expf(s01 - mn0);
        const float p10 = __expf(s10 - mn1), p11 = __expf(s11 - mn1);
        float t0 = p00 + p01, t1 = p10 + p11;
        #pragma unroll
        for (int off = 1; off <= 16; off <<= 1) {
            t0 += __shfl_xor(t0, off, 64);
            t1 += __shfl_xor(t1, off, 64);
        }
        p_lds[sq][sm]      = p00; p_lds[sq][sm + 32]     = p01;
        p_lds[sq + 1][sm]  = p10; p_lds[sq + 1][sm + 32] = p11;
        if (sm == 0) {
            const float sc0 = __expf(mold0 - mn0), sc1 = __expf(mold1 - mn1);
            m_lds[sq] = mn0; m_lds[sq + 1] = mn1;
            l_lds[sq]     = l_lds[sq]     * sc0 + t0;
            l_lds[sq + 1] = l_lds[sq + 1] * sc1 + t1;
            scale_lds[sq] = sc0; scale_lds[sq + 1] = sc1;
        }
        __syncthreads();

        const float sc = scale_lds[pq];
        #pragma unroll
        for (int e = 0; e < 8; ++e) acc[e] *= sc;
        #pragma unroll 8
        for (int m = 0; m < MT; ++m) {
            const float p = p_lds[pq][m];
            const float4 va = *reinterpret_cast<const float4*>(&mem_lds[m][pf]);
            const float4 vb = *reinterpret_cast<const float4*>(&mem_lds[m][pf + 64]);
            acc[0] += p * va.x; acc[1] += p * va.y; acc[2] += p * va.z; acc[3] += p * va.w;
            acc[4] += p * vb.x; acc[5] += p * vb.y; acc[6] += p * vb.z; acc[7] += p * vb.w;
        }
    }
    const float linv = 1.0f / l_lds[pq];
    float4 o0 = {acc[0]*linv, acc[1]*linv, acc[2]*linv, acc[3]*linv};
    float4 o1 = {acc[4]*linv, acc[5]*linv, acc[6]*linv, acc[7]*linv};
    *reinterpret_cast<float4*>(&Out[(size_t)(qblk + pq) * FDIM + pf]) = o0;
    *reinterpret_cast<float4*>(&Out[(size_t)(qblk + pq) * FDIM + pf + 64]) = o1;
    if (tid < QT) Conf[qblk + tid] = 1.0f / l_lds[tid];
}

extern "C" void kernel_launch(void* const* d_in, const int* in_sizes, int n_in,
                              void* d_out, int out_size, void* d_ws, size_t ws_size,
                              hipStream_t stream) {
    (void)in_sizes; (void)n_in; (void)out_size;
    const float* memory   = (const float*)d_in[0];
    const float* input    = (const float*)d_in[1];
    const float* wweights = (const float*)d_in[2];
    const float* query    = (const float*)d_in[3];

    float* out       = (float*)d_out;
    float* retrieved = out;
    float* conf      = out + (size_t)BATCH * FDIM;
    float* mem_new   = conf + BATCH;

    char* ws = (char*)d_ws;
    float* inv_s = (float*)ws;

    const size_t off_xt   = 16384;
    const size_t off_part = off_xt + ((size_t)FDIM * BATCH * 2);          // XT64: 1 MiB
    const size_t off_h    = off_part + ((size_t)256 * BATCH * 4);         // partial: 4 MiB
    const size_t off_hT   = off_h + ((size_t)MEMSZ * FDIM * 2);           // MemH: 8 MiB
    const size_t off_pc   = off_hT + ((size_t)MEMSZ * FDIM * 2);          // MemHT: 8 MiB
    const size_t sz_pc    = (size_t)16 * ((size_t)BATCH * 8 + (size_t)BATCH * FDIM * 4);
    const size_t off_wt   = off_pc + sz_pc;
    const size_t need     = off_wt + (size_t)64 * 256 * 16384;            // WT64: 256 MiB

    if (ws_size >= need) {
        unsigned char* xt64 = (unsigned char*)(ws + off_xt);
        float* part = (float*)(ws + off_part);
        u16t* mh    = (u16t*)(ws + off_h);
        u16t* mhT   = (u16t*)(ws + off_hT);
        float* mP   = (float*)(ws + off_pc);
        float* lP   = mP + (size_t)16 * BATCH;
        float* accP = lP + (size_t)16 * BATCH;
        unsigned char* wt64 = (unsigned char*)(ws + off_wt);

        k_sumT<<<64 * 256, 256, 0, stream>>>(wweights, part, wt64);
        k_inv<<<BATCH / 256, 256, 0, stream>>>(part, inv_s);
        k_prep<<<BATCH / 64, 256, 0, stream>>>(input, inv_s, xt64);
        k_update_mfma2<<<MEMSZ / 128, 512, 0, stream>>>(wt64, xt64, memory, mem_new, mh, mhT);
        k_attn_mfma<<<(BATCH / 128) * 16, 256, 0, stream>>>(query, mh, mhT, accP, mP, lP, 4);
        k_combine<<<BATCH / 8, 256, 0, stream>>>(mP, lP, accP, retrieved, conf, 16);
    } else {
        k_rowsum<<<BATCH, 256, 0, stream>>>(wweights, inv_s);
        k_update_f32<<<MEMSZ / K2_MT, 256, 0, stream>>>(wweights, input, inv_s, memory, mem_new);
        k_attn_f32<<<BATCH / QT, 256, 0, stream>>>(query, mem_new, retrieved, conf);
    }
}

// Round 7
// 399.345 us; speedup vs baseline: 1.1978x; 1.1978x over previous
//
#include <hip/hip_runtime.h>
#include <hip/hip_bf16.h>
#include <math.h>

#define MEMSZ 32768
#define FDIM  128
#define BATCH 4096

typedef float f32x4 __attribute__((ext_vector_type(4)));
typedef _Float16 f16x8 __attribute__((ext_vector_type(8)));
typedef short bf16x8 __attribute__((ext_vector_type(8)));
typedef unsigned short u16t;
typedef unsigned int u32t;

static __device__ __forceinline__ u16t f2h_bits(float f) {
    union { _Float16 h; u16t u; } c;
    c.h = (_Float16)f;
    return c.u;
}

#define GLDS16(gsrc, ldst) \
  __builtin_amdgcn_global_load_lds((const __attribute__((address_space(1))) void*)(gsrc), \
                                   (__attribute__((address_space(3))) void*)(ldst), 16, 0, 0)

// ---------------- K1: row sums of write_weights -> inv_s ----------------
__global__ __launch_bounds__(256) void k_rowsum(const float* __restrict__ W,
                                                float* __restrict__ inv_s) {
    const int row = blockIdx.x;
    const float4* Wr = reinterpret_cast<const float4*>(W + (size_t)row * MEMSZ);
    float acc = 0.f;
    #pragma unroll 4
    for (int i = threadIdx.x; i < MEMSZ / 4; i += 256) {
        float4 v = Wr[i];
        acc += (v.x + v.y) + (v.z + v.w);
    }
    #pragma unroll
    for (int off = 32; off > 0; off >>= 1)
        acc += __shfl_down(acc, off, 64);
    __shared__ float wsum[4];
    const int lane = threadIdx.x & 63, wid = threadIdx.x >> 6;
    if (lane == 0) wsum[wid] = acc;
    __syncthreads();
    if (threadIdx.x == 0)
        inv_s[row] = 1.0f / (wsum[0] + wsum[1] + wsum[2] + wsum[3]);
}

// ---------------- K1b: XT64 = fragment-major bf16(X * inv_s) ----------------
__global__ __launch_bounds__(256) void k_prep(const float* __restrict__ X,
                                              const float* __restrict__ inv_s,
                                              unsigned char* __restrict__ XT64) {
    __shared__ float xs[64][132];
    const int T = blockIdx.x;
    const int b0 = T * 64;
    const int tid = threadIdx.x;
    #pragma unroll
    for (int i = 0; i < 8; ++i) {
        const int idx = tid + i * 256;
        const int row = idx >> 5, c4 = idx & 31;
        const float s = inv_s[b0 + row];
        float4 v = *reinterpret_cast<const float4*>(&X[(size_t)(b0 + row) * FDIM + c4 * 4]);
        v.x *= s; v.y *= s; v.z *= s; v.w *= s;
        *reinterpret_cast<float4*>(&xs[row][c4 * 4]) = v;
    }
    __syncthreads();
    #pragma unroll
    for (int i = 0; i < 4; ++i) {
        const int L = tid + i * 256;
        const int fh = L >> 9, ff = (L >> 7) & 3, ks = (L >> 6) & 1, ln = L & 63;
        const int f = fh * 64 + ff * 16 + (ln & 15);
        const int bi = ks * 32 + (ln >> 4) * 8;
        u32t pk[4];
        #pragma unroll
        for (int h = 0; h < 4; ++h) {
            const float lo = xs[bi + 2 * h][f];
            const float hi = xs[bi + 2 * h + 1][f];
            asm("v_cvt_pk_bf16_f32 %0, %1, %2" : "=v"(pk[h]) : "v"(lo), "v"(hi));
        }
        *reinterpret_cast<uint4*>(XT64 + (size_t)T * 16384 + (size_t)L * 16) =
            make_uint4(pk[0], pk[1], pk[2], pk[3]);
    }
}

// ---------------- K2 (MFMA): MemNew = Mem + W^T @ (X*inv_s), + f16 copies ----------------
// 512 blocks x 256 threads (2 blocks/CU); block tile 64m x 128f; K-step 64 b.
// W: 2x16KB LDS dbuf via global_load_lds w16, swizzle byte^=(b&8)<<1 (2-way-free A reads).
// Pipeline: loadB(t+1); stageW(t+1); vmcnt(12); barrier; compute(t) - 12 newest stay in flight.
#define K2B 64
#define K2M 64
__global__ __launch_bounds__(256, 2) void k_update_mfma(
    const float* __restrict__ W, const unsigned char* __restrict__ XT64,
    const float* __restrict__ Mem, float* __restrict__ MemNew,
    u16t* __restrict__ MemH, u16t* __restrict__ MemHT)
{
    __shared__ __align__(16) unsigned char wt[2][16384];   // [64 b][64 m] f32, swizzled

    const int tid = threadIdx.x;
    const int lane = tid & 63, w = tid >> 6;
    const int q16 = lane & 15, g = lane >> 4;
    const int wm = w >> 1, wf = w & 1;       // wave tile: 32 m x 64 f
    const int mblk = blockIdx.x * K2M;

    f32x4 acc[2][4];
    #pragma unroll
    for (int mf = 0; mf < 2; ++mf)
        #pragma unroll
        for (int ff = 0; ff < 4; ++ff) acc[mf][ff] = (f32x4){0.f, 0.f, 0.f, 0.f};

    const unsigned char* xbase = XT64 + (size_t)(wf * 8192 + lane * 16);

    auto stageW = [&](int buf, int t) {
        const int b0 = t * K2B;
        #pragma unroll
        for (int c = 0; c < 4; ++c) {
            const int gi = c * 256 + tid;         // 1024 granules: 64 rows x 16
            const int b = gi >> 4;
            const int src = ((gi & 15) * 16) ^ ((b & 8) << 1);   // inverse-swizzled source
            GLDS16((const unsigned char*)W + (size_t)(b0 + b) * (MEMSZ * 4) + (size_t)mblk * 4 + src,
                   &wt[buf][gi * 16]);
        }
    };
    auto loadB = [&](bf16x8 (&br)[4][2], int t) {
        const unsigned char* xp = xbase + (size_t)t * 16384;
        #pragma unroll
        for (int ff = 0; ff < 4; ++ff)
            #pragma unroll
            for (int ks = 0; ks < 2; ++ks)
                br[ff][ks] = *reinterpret_cast<const bf16x8*>(xp + ff * 2048 + ks * 1024);
    };
    auto compute = [&](int buf, bf16x8 (&br)[4][2]) {
        bf16x8 afr[2][2];
        const unsigned char* tb = &wt[buf][0];
        #pragma unroll
        for (int mf = 0; mf < 2; ++mf) {
            const int mm4 = (wm * 32 + mf * 16 + q16) * 4;
            #pragma unroll
            for (int ks = 0; ks < 2; ++ks) {
                float av[8];
                #pragma unroll
                for (int e = 0; e < 8; ++e) {
                    const int b = ks * 32 + g * 8 + e;
                    av[e] = *reinterpret_cast<const float*>(
                        tb + b * 256 + (mm4 ^ ((b & 8) << 1)));
                }
                union { u32t u[4]; bf16x8 v; } cv;
                #pragma unroll
                for (int h = 0; h < 4; ++h)
                    asm("v_cvt_pk_bf16_f32 %0, %1, %2" : "=v"(cv.u[h]) : "v"(av[2 * h]), "v"(av[2 * h + 1]));
                afr[mf][ks] = cv.v;
            }
        }
        #pragma unroll
        for (int mf = 0; mf < 2; ++mf)
            #pragma unroll
            for (int ff = 0; ff < 4; ++ff)
                #pragma unroll
                for (int ks = 0; ks < 2; ++ks)
                    acc[mf][ff] = __builtin_amdgcn_mfma_f32_16x16x32_bf16(
                        afr[mf][ks], br[ff][ks], acc[mf][ff], 0, 0, 0);
    };

    bf16x8 bA[4][2], bB_[4][2];
    stageW(0, 0); loadB(bA, 0);
    const int NT = BATCH / K2B;   // 64, even
    for (int t = 0; t < NT; t += 2) {
        // ---- even tile t: buf 0, regs bA ----
        __builtin_amdgcn_s_barrier();                       // compute(t-1) done -> buf 1 free
        if (t + 1 < NT) { loadB(bB_, t + 1); stageW(1, t + 1); }
        if (t + 1 < NT) asm volatile("s_waitcnt vmcnt(12)" ::: "memory");
        else            asm volatile("s_waitcnt vmcnt(0)"  ::: "memory");
        __builtin_amdgcn_s_barrier();                       // tile t resident everywhere
        __builtin_amdgcn_sched_barrier(0);
        compute(0, bA);
        // ---- odd tile t+1: buf 1, regs bB_ ----
        __builtin_amdgcn_s_barrier();                       // compute(t) done -> buf 0 free
        if (t + 2 < NT) { loadB(bA, t + 2); stageW(0, t + 2); }
        if (t + 2 < NT) asm volatile("s_waitcnt vmcnt(12)" ::: "memory");
        else            asm volatile("s_waitcnt vmcnt(0)"  ::: "memory");
        __builtin_amdgcn_s_barrier();
        __builtin_amdgcn_sched_barrier(0);
        compute(1, bB_);
    }

    // epilogue: add memory; write f32 MemNew + f16 MemH + f16-transposed MemHT
    #pragma unroll
    for (int mf = 0; mf < 2; ++mf) {
        #pragma unroll
        for (int ff = 0; ff < 4; ++ff) {
            const int m0 = mblk + wm * 32 + mf * 16 + g * 4;
            const int fcol = wf * 64 + ff * 16 + q16;
            ushort4 ht;
            u16t* htp = reinterpret_cast<u16t*>(&ht);
            #pragma unroll
            for (int r = 0; r < 4; ++r) {
                const size_t idx = (size_t)(m0 + r) * FDIM + fcol;
                const float v = acc[mf][ff][r] + Mem[idx];
                MemNew[idx] = v;
                const u16t hb = f2h_bits(v);
                MemH[idx] = hb;
                htp[r] = hb;
            }
            *reinterpret_cast<ushort4*>(&MemHT[(size_t)fcol * MEMSZ + m0]) = ht;
        }
    }
}

// ---------------- fallback f32 K2 (round-1, known-good) ----------------
#define K2_IT 16
#define K2_MT 64
__global__ __launch_bounds__(256) void k_update_f32(const float* __restrict__ W,
                                                    const float* __restrict__ X,
                                                    const float* __restrict__ inv_s,
                                                    const float* __restrict__ Mem,
                                                    float* __restrict__ MemNew) {
    __shared__ float w_lds[2][K2_IT][K2_MT];
    __shared__ float x_lds[2][K2_IT][FDIM];
    const int j0 = blockIdx.x * K2_MT;
    const int tid = threadIdx.x;
    const int tf = tid & 15;
    const int tj = tid >> 4;

    float acc[4][8];
    #pragma unroll
    for (int a = 0; a < 4; ++a)
        #pragma unroll
        for (int b = 0; b < 8; ++b) acc[a][b] = 0.f;

    float4 pw, px0, px1;
    float ps0, ps1;
    const int wr = tid >> 4, wc4 = tid & 15;
    const int xr0 = tid >> 5, xc0 = tid & 31;
    const int xr1 = (tid + 256) >> 5, xc1 = tid & 31;

    auto load_tile = [&](int it) {
        const int i0 = it * K2_IT;
        pw  = *reinterpret_cast<const float4*>(&W[(size_t)(i0 + wr) * MEMSZ + j0 + wc4 * 4]);
        px0 = *reinterpret_cast<const float4*>(&X[(size_t)(i0 + xr0) * FDIM + xc0 * 4]);
        ps0 = inv_s[i0 + xr0];
        px1 = *reinterpret_cast<const float4*>(&X[(size_t)(i0 + xr1) * FDIM + xc1 * 4]);
        ps1 = inv_s[i0 + xr1];
    };
    auto write_tile = [&](int buf) {
        *reinterpret_cast<float4*>(&w_lds[buf][wr][wc4 * 4]) = pw;
        float4 v = px0; v.x *= ps0; v.y *= ps0; v.z *= ps0; v.w *= ps0;
        *reinterpret_cast<float4*>(&x_lds[buf][xr0][xc0 * 4]) = v;
        float4 u = px1; u.x *= ps1; u.y *= ps1; u.z *= ps1; u.w *= ps1;
        *reinterpret_cast<float4*>(&x_lds[buf][xr1][xc1 * 4]) = u;
    };

    load_tile(0);
    write_tile(0);
    __syncthreads();
    const int NT = BATCH / K2_IT;
    for (int it = 0; it < NT; ++it) {
        const int cur = it & 1;
        if (it + 1 < NT) load_tile(it + 1);
        #pragma unroll 4
        for (int i = 0; i < K2_IT; ++i) {
            const float4 wv = *reinterpret_cast<const float4*>(&w_lds[cur][i][tj * 4]);
            const float4 xa = *reinterpret_cast<const float4*>(&x_lds[cur][i][tf * 4]);
            const float4 xb = *reinterpret_cast<const float4*>(&x_lds[cur][i][tf * 4 + 64]);
            const float wj[4] = {wv.x, wv.y, wv.z, wv.w};
            #pragma unroll
            for (int a = 0; a < 4; ++a) {
                acc[a][0] += wj[a] * xa.x; acc[a][1] += wj[a] * xa.y;
                acc[a][2] += wj[a] * xa.z; acc[a][3] += wj[a] * xa.w;
                acc[a][4] += wj[a] * xb.x; acc[a][5] += wj[a] * xb.y;
                acc[a][6] += wj[a] * xb.z; acc[a][7] += wj[a] * xb.w;
            }
        }
        if (it + 1 < NT) write_tile(cur ^ 1);
        __syncthreads();
    }
    #pragma unroll
    for (int a = 0; a < 4; ++a) {
        const size_t j = (size_t)j0 + tj * 4 + a;
        const float4 m0 = *reinterpret_cast<const float4*>(&Mem[j * FDIM + tf * 4]);
        const float4 m1 = *reinterpret_cast<const float4*>(&Mem[j * FDIM + tf * 4 + 64]);
        float4 o0 = {acc[a][0] + m0.x, acc[a][1] + m0.y, acc[a][2] + m0.z, acc[a][3] + m0.w};
        float4 o1 = {acc[a][4] + m1.x, acc[a][5] + m1.y, acc[a][6] + m1.z, acc[a][7] + m1.w};
        *reinterpret_cast<float4*>(&MemNew[j * FDIM + tf * 4]) = o0;
        *reinterpret_cast<float4*>(&MemNew[j * FDIM + tf * 4 + 64]) = o1;
    }
}

// ---------------- K3 (MFMA f16): flash attention partials over chunks ----------------
__global__ __launch_bounds__(256) void k_attn_mfma(
    const float* __restrict__ Q, const u16t* __restrict__ Kh, const u16t* __restrict__ KhT,
    float* __restrict__ accP, float* __restrict__ mP, float* __restrict__ lP, int s_shift)
{
    __shared__ __align__(16) unsigned char kv_u8[2][16384];
    __shared__ __align__(16) unsigned char v_u8[2][16384];
    __shared__ __align__(16) unsigned char p_u8[4][2048];

    const int tid = threadIdx.x;
    const int w = tid >> 6, lane = tid & 63;
    const int q16 = lane & 15, g = lane >> 4;
    const int S = 1 << s_shift;
    const int s_idx = blockIdx.x & (S - 1);
    const int qb = blockIdx.x >> s_shift;
    const int chunk = MEMSZ >> s_shift;
    const int slot0 = s_idx * chunk;
    const int NT = chunk >> 6;

    f16x8 qfrag[2][4];
    #pragma unroll
    for (int qf = 0; qf < 2; ++qf) {
        const float* qrow = Q + (size_t)(qb * 128 + w * 32 + qf * 16 + q16) * FDIM;
        #pragma unroll
        for (int ks = 0; ks < 4; ++ks) {
            float tmp[8];
            *reinterpret_cast<float4*>(&tmp[0]) = *reinterpret_cast<const float4*>(&qrow[ks * 32 + g * 8]);
            *reinterpret_cast<float4*>(&tmp[4]) = *reinterpret_cast<const float4*>(&qrow[ks * 32 + g * 8 + 4]);
            f16x8 v;
            #pragma unroll
            for (int e = 0; e < 8; ++e) v[e] = (_Float16)tmp[e];
            qfrag[qf][ks] = v;
        }
    }

    auto stage = [&](int buf, int tile) {
        const unsigned char* kbase = (const unsigned char*)Kh + (size_t)(slot0 + tile * 64) * 256;
        const unsigned char* tbase = (const unsigned char*)KhT + (size_t)(slot0 + tile * 64) * 2;
        #pragma unroll
        for (int c = 0; c < 4; ++c) {
            const int C = w * 4 + c;
            const int pp = C * 1024 + lane * 16;
            {
                const int slot = pp >> 8;
                const int inner = (pp & 255) ^ ((slot & 7) << 4);
                GLDS16(kbase + slot * 256 + inner, &kv_u8[buf][C * 1024]);
            }
            {
                const int d = pp >> 7;
                const int inner = (pp & 127) ^ ((d & 7) << 4);
                GLDS16(tbase + (size_t)d * 65536 + inner, &v_u8[buf][C * 1024]);
            }
        }
    };

    float m_run[2] = {-3.0e38f, -3.0e38f};
    float l_run[2] = {0.f, 0.f};
    f32x4 acc_o[8][2];
    #pragma unroll
    for (int df = 0; df < 8; ++df)
        #pragma unroll
        for (int qf = 0; qf < 2; ++qf)
            acc_o[df][qf] = (f32x4){0.f, 0.f, 0.f, 0.f};

    stage(0, 0);
    asm volatile("s_waitcnt vmcnt(0)" ::: "memory");
    __builtin_amdgcn_s_barrier();
    __builtin_amdgcn_sched_barrier(0);

    int cur = 0;
    for (int t = 0; t < NT; ++t) {
        if (t + 1 < NT) stage(cur ^ 1, t + 1);

        f32x4 acc_s[4][2];
        #pragma unroll
        for (int sf = 0; sf < 4; ++sf) {
            acc_s[sf][0] = (f32x4){0.f, 0.f, 0.f, 0.f};
            acc_s[sf][1] = (f32x4){0.f, 0.f, 0.f, 0.f};
        }
        const unsigned char* kvb = &kv_u8[cur][0];
        #pragma unroll
        for (int ks = 0; ks < 4; ++ks) {
            #pragma unroll
            for (int sf = 0; sf < 4; ++sf) {
                const int slot = sf * 16 + q16;
                const f16x8 a = *reinterpret_cast<const f16x8*>(
                    kvb + slot * 256 + ((ks * 64 + g * 16) ^ ((slot & 7) << 4)));
                acc_s[sf][0] = __builtin_amdgcn_mfma_f32_16x16x32_f16(a, qfrag[0][ks], acc_s[sf][0], 0, 0, 0);
                acc_s[sf][1] = __builtin_amdgcn_mfma_f32_16x16x32_f16(a, qfrag[1][ks], acc_s[sf][1], 0, 0, 0);
            }
        }

        f16x8 pb[2][2];
        unsigned char* pw = &p_u8[w][0];
        #pragma unroll
        for (int qf = 0; qf < 2; ++qf) {
            float pmax = acc_s[0][qf][0];
            #pragma unroll
            for (int sf = 0; sf < 4; ++sf)
                #pragma unroll
                for (int r = 0; r < 4; ++r)
                    pmax = fmaxf(pmax, acc_s[sf][qf][r]);
            pmax = fmaxf(pmax, __shfl_xor(pmax, 16));
            pmax = fmaxf(pmax, __shfl_xor(pmax, 32));
            const float mn = fmaxf(m_run[qf], pmax);
            float p[4][4];
            float psum = 0.f;
            #pragma unroll
            for (int sf = 0; sf < 4; ++sf)
                #pragma unroll
                for (int r = 0; r < 4; ++r) {
                    p[sf][r] = __expf(acc_s[sf][qf][r] - mn);
                    psum += p[sf][r];
                }
            psum += __shfl_xor(psum, 16);
            psum += __shfl_xor(psum, 32);
            const float sc = __expf(m_run[qf] - mn);
            l_run[qf] = l_run[qf] * sc + psum;
            m_run[qf] = mn;
            #pragma unroll
            for (int df = 0; df < 8; ++df) {
                acc_o[df][qf][0] *= sc; acc_o[df][qf][1] *= sc;
                acc_o[df][qf][2] *= sc; acc_o[df][qf][3] *= sc;
            }
            #pragma unroll
            for (int sf = 0; sf < 4; ++sf)
                #pragma unroll
                for (int rr = 0; rr < 2; ++rr) {
                    const u32t val = (u32t)f2h_bits(p[sf][2 * rr]) | ((u32t)f2h_bits(p[sf][2 * rr + 1]) << 16);
                    const int byte = q16 * 128 + (((sf * 16 + g * 4 + 2 * rr) * 2) ^ ((q16 & 7) << 4));
                    *reinterpret_cast<u32t*>(pw + byte) = val;
                }
            #pragma unroll
            for (int kk = 0; kk < 2; ++kk) {
                const int byte = q16 * 128 + (((kk * 32 + g * 8) * 2) ^ ((q16 & 7) << 4));
                pb[qf][kk] = *reinterpret_cast<const f16x8*>(pw + byte);
            }
        }

        const unsigned char* vb = &v_u8[cur][0];
        #pragma unroll
        for (int df = 0; df < 8; ++df) {
            #pragma unroll
            for (int kk = 0; kk < 2; ++kk) {
                const int d = df * 16 + q16;
                const f16x8 av = *reinterpret_cast<const f16x8*>(
                    vb + d * 128 + ((kk * 64 + g * 16) ^ ((d & 7) << 4)));
                acc_o[df][0] = __builtin_amdgcn_mfma_f32_16x16x32_f16(av, pb[0][kk], acc_o[df][0], 0, 0, 0);
                acc_o[df][1] = __builtin_amdgcn_mfma_f32_16x16x32_f16(av, pb[1][kk], acc_o[df][1], 0, 0, 0);
            }
        }

        asm volatile("s_waitcnt vmcnt(0)" ::: "memory");
        __builtin_amdgcn_s_barrier();
        __builtin_amdgcn_sched_barrier(0);
        cur ^= 1;
    }

    const int rowbase = qb * 128 + w * 32;
    #pragma unroll
    for (int qf = 0; qf < 2; ++qf) {
        const int row = rowbase + qf * 16 + q16;
        float* ap = accP + ((size_t)s_idx * BATCH + row) * FDIM;
        #pragma unroll
        for (int df = 0; df < 8; ++df) {
            float4 o = {acc_o[df][qf][0], acc_o[df][qf][1], acc_o[df][qf][2], acc_o[df][qf][3]};
            *reinterpret_cast<float4*>(&ap[df * 16 + g * 4]) = o;
        }
        if (g == 0) {
            mP[(size_t)s_idx * BATCH + row] = m_run[qf];
            lP[(size_t)s_idx * BATCH + row] = l_run[qf];
        }
    }
}

// ---------------- K4: combine chunk partials ----------------
__global__ __launch_bounds__(256) void k_combine(const float* __restrict__ mP,
                                                 const float* __restrict__ lP,
                                                 const float* __restrict__ accP,
                                                 float* __restrict__ Out,
                                                 float* __restrict__ Conf, int S) {
    const int row = blockIdx.x * 8 + (threadIdx.x >> 5);
    const int lane = threadIdx.x & 31;
    float mt = -3.0e38f;
    for (int s = 0; s < S; ++s) mt = fmaxf(mt, mP[(size_t)s * BATCH + row]);
    float lt = 0.f;
    for (int s = 0; s < S; ++s) lt += lP[(size_t)s * BATCH + row] * __expf(mP[(size_t)s * BATCH + row] - mt);
    const float inv = 1.0f / lt;
    float4 o = {0.f, 0.f, 0.f, 0.f};
    for (int s = 0; s < S; ++s) {
        const float wgt = __expf(mP[(size_t)s * BATCH + row] - mt);
        const float4 a = *reinterpret_cast<const float4*>(&accP[((size_t)s * BATCH + row) * FDIM + lane * 4]);
        o.x += wgt * a.x; o.y += wgt * a.y; o.z += wgt * a.z; o.w += wgt * a.w;
    }
    float4 res = {o.x * inv, o.y * inv, o.z * inv, o.w * inv};
    *reinterpret_cast<float4*>(&Out[(size_t)row * FDIM + lane * 4]) = res;
    if (lane == 0) Conf[row] = inv;
}

// ---------------- fallback f32 attention (round-1, known-good) ----------------
#define QT 16
#define MT 64
#define LSTR (FDIM + 4)
__global__ __launch_bounds__(256) void k_attn_f32(const float* __restrict__ Q,
                                                  const float* __restrict__ MemNew,
                                                  float* __restrict__ Out,
                                                  float* __restrict__ Conf) {
    __shared__ float mem_lds[MT][LSTR];
    __shared__ float q_lds[QT][LSTR];
    __shared__ float p_lds[QT][MT];
    __shared__ float m_lds[QT], l_lds[QT], scale_lds[QT];

    const int tid = threadIdx.x;
    const int qblk = blockIdx.x * QT;

    #pragma unroll
    for (int r = 0; r < 2; ++r) {
        const int idx = tid + r * 256;
        const int row = idx >> 5, c4 = idx & 31;
        *reinterpret_cast<float4*>(&q_lds[row][c4 * 4]) =
            *reinterpret_cast<const float4*>(&Q[(size_t)(qblk + row) * FDIM + c4 * 4]);
    }
    if (tid < QT) { m_lds[tid] = -3.0e38f; l_lds[tid] = 0.f; }

    const int sq = (tid >> 5) * 2;
    const int sm = tid & 31;
    const int pq = tid >> 4;
    const int pf = (tid & 15) * 4;

    float acc[8];
    #pragma unroll
    for (int e = 0; e < 8; ++e) acc[e] = 0.f;

    for (int mt = 0; mt < MEMSZ / MT; ++mt) {
        __syncthreads();
        const float* src = MemNew + (size_t)mt * MT * FDIM;
        #pragma unroll
        for (int r = 0; r < 8; ++r) {
            const int idx = tid + r * 256;
            const int row = idx >> 5, c4 = idx & 31;
            *reinterpret_cast<float4*>(&mem_lds[row][c4 * 4]) =
                *reinterpret_cast<const float4*>(&src[(size_t)row * FDIM + c4 * 4]);
        }
        const float mold0 = m_lds[sq], mold1 = m_lds[sq + 1];
        __syncthreads();

        float s00 = 0.f, s01 = 0.f, s10 = 0.f, s11 = 0.f;
        #pragma unroll 8
        for (int k = 0; k < FDIM; k += 4) {
            const float4 qa = *reinterpret_cast<const float4*>(&q_lds[sq][k]);
            const float4 qb = *reinterpret_cast<const float4*>(&q_lds[sq + 1][k]);
            const float4 ma = *reinterpret_cast<const float4*>(&mem_lds[sm][k]);
            const float4 mb = *reinterpret_cast<const float4*>(&mem_lds[sm + 32][k]);
            s00 += qa.x*ma.x + qa.y*ma.y + qa.z*ma.z + qa.w*ma.w;
            s01 += qa.x*mb.x + qa.y*mb.y + qa.z*mb.z + qa.w*mb.w;
            s10 += qb.x*ma.x + qb.y*ma.y + qb.z*ma.z + qb.w*ma.w;
            s11 += qb.x*mb.x + qb.y*mb.y + qb.z*mb.z + qb.w*mb.w;
        }
        float r0 = fmaxf(s00, s01), r1 = fmaxf(s10, s11);
        #pragma unroll
        for (int off = 1; off <= 16; off <<= 1) {
            r0 = fmaxf(r0, __shfl_xor(r0, off, 64));
            r1 = fmaxf(r1, __shfl_xor(r1, off, 64));
        }
        const float mn0 = fmaxf(mold0, r0), mn1 = fmaxf(mold1, r1);
        const float p00 = __expf(s00 - mn0), p01 = __expf(s01 - mn0);
        const float p10 = __expf(s10 - mn1), p11 = __expf(s11 - mn1);
        float t0 = p00 + p01, t1 = p10 + p11;
        #pragma unroll
        for (int off = 1; off <= 16; off <<= 1) {
            t0 += __shfl_xor(t0, off, 64);
            t1 += __shfl_xor(t1, off, 64);
        }
        p_lds[sq][sm]      = p00; p_lds[sq][sm + 32]     = p01;
        p_lds[sq + 1][sm]  = p10; p_lds[sq + 1][sm + 32] = p11;
        if (sm == 0) {
            const float sc0 = __expf(mold0 - mn0), sc1 = __expf(mold1 - mn1);
            m_lds[sq] = mn0; m_lds[sq + 1] = mn1;
            l_lds[sq]     = l_lds[sq]     * sc0 + t0;
            l_lds[sq + 1] = l_lds[sq + 1] * sc1 + t1;
            scale_lds[sq] = sc0; scale_lds[sq + 1] = sc1;
        }
        __syncthreads();

        const float sc = scale_lds[pq];
        #pragma unroll
        for (int e = 0; e < 8; ++e) acc[e] *= sc;
        #pragma unroll 8
        for (int m = 0; m < MT; ++m) {
            const float p = p_lds[pq][m];
            const float4 va = *reinterpret_cast<const float4*>(&mem_lds[m][pf]);
            const float4 vb = *reinterpret_cast<const float4*>(&mem_lds[m][pf + 64]);
            acc[0] += p * va.x; acc[1] += p * va.y; acc[2] += p * va.z; acc[3] += p * va.w;
            acc[4] += p * vb.x; acc[5] += p * vb.y; acc[6] += p * vb.z; acc[7] += p * vb.w;
        }
    }
    const float linv = 1.0f / l_lds[pq];
    float4 o0 = {acc[0]*linv, acc[1]*linv, acc[2]*linv, acc[3]*linv};
    float4 o1 = {acc[4]*linv, acc[5]*linv, acc[6]*linv, acc[7]*linv};
    *reinterpret_cast<float4*>(&Out[(size_t)(qblk + pq) * FDIM + pf]) = o0;
    *reinterpret_cast<float4*>(&Out[(size_t)(qblk + pq) * FDIM + pf + 64]) = o1;
    if (tid < QT) Conf[qblk + tid] = 1.0f / l_lds[tid];
}

extern "C" void kernel_launch(void* const* d_in, const int* in_sizes, int n_in,
                              void* d_out, int out_size, void* d_ws, size_t ws_size,
                              hipStream_t stream) {
    (void)in_sizes; (void)n_in; (void)out_size;
    const float* memory   = (const float*)d_in[0];
    const float* input    = (const float*)d_in[1];
    const float* wweights = (const float*)d_in[2];
    const float* query    = (const float*)d_in[3];

    float* out       = (float*)d_out;
    float* retrieved = out;
    float* conf      = out + (size_t)BATCH * FDIM;
    float* mem_new   = conf + BATCH;

    char* ws = (char*)d_ws;
    float* inv_s = (float*)ws;
    const size_t off_xt   = 16384;
    const size_t off_h    = off_xt + (size_t)FDIM * BATCH * 2;      // XT64: 1 MiB
    const size_t off_hT   = off_h + (size_t)MEMSZ * FDIM * 2;
    const size_t off_part = off_hT + (size_t)MEMSZ * FDIM * 2;

    int s_shift = -1;
    for (int sh = 4; sh >= 0; --sh) {
        const size_t S = (size_t)1 << sh;
        const size_t need = off_part + S * ((size_t)BATCH * 8 + (size_t)BATCH * FDIM * 4);
        if (ws_size >= need) { s_shift = sh; break; }
    }

    k_rowsum<<<BATCH, 256, 0, stream>>>(wweights, inv_s);
    if (s_shift >= 0) {
        const int S = 1 << s_shift;
        unsigned char* xt64 = (unsigned char*)(ws + off_xt);
        u16t* mh  = (u16t*)(ws + off_h);
        u16t* mhT = (u16t*)(ws + off_hT);
        float* mP   = (float*)(ws + off_part);
        float* lP   = mP + (size_t)S * BATCH;
        float* accP = lP + (size_t)S * BATCH;
        k_prep<<<BATCH / 64, 256, 0, stream>>>(input, inv_s, xt64);
        k_update_mfma<<<MEMSZ / K2M, 256, 0, stream>>>(wweights, xt64, memory, mem_new, mh, mhT);
        k_attn_mfma<<<(BATCH / 128) * S, 256, 0, stream>>>(query, mh, mhT, accP, mP, lP, s_shift);
        k_combine<<<BATCH / 8, 256, 0, stream>>>(mP, lP, accP, retrieved, conf, S);
    } else {
        k_update_f32<<<MEMSZ / K2_MT, 256, 0, stream>>>(wweights, input, inv_s, memory, mem_new);
        k_attn_f32<<<BATCH / QT, 256, 0, stream>>>(query, mem_new, retrieved, conf);
    }
}